// Round 1
// baseline (83.729 us; speedup 1.0000x reference)
//
#include <hip/hip_runtime.h>

// DecisionTreePolicy: complete binary tree, depth 15 (32767 nodes).
// Internal nodes: 0..16382 (children are always 2i+1 / 2i+2).
// Leaves: 16383..32766. Traversal = exactly 14 steps from root.
// out[b] = leaf_logits[leaf_id(b)]  (64 floats per element).

#define N_NODES   32767
#define N_INTERN  16383
#define N_FEAT    256
#define N_ACT     64
#define BATCH     262144
#define BLOCK     1024
#define DEPTH     14

__global__ __launch_bounds__(BLOCK) void tree_policy_kernel(
    const float* __restrict__ obs,          // [BATCH][N_FEAT]
    const int*   __restrict__ features,     // [N_NODES]
    const float* __restrict__ thresholds,   // [N_NODES]
    const float* __restrict__ leaf_logits,  // [N_NODES][N_ACT]
    float*       __restrict__ out)          // [BATCH][N_ACT]
{
    // Packed tree node: .x = threshold (f32), .y = feature index (int bits).
    // 16384 * 8 B = 128 KiB LDS (gfx950 has 160 KiB/CU; 1 block/CU).
    __shared__ float2 nodes[N_INTERN + 1];

    const int tid = threadIdx.x;

    // Cooperative stage: coalesced reads of thresholds/features (L2-hot).
    for (int i = tid; i < N_INTERN; i += BLOCK) {
        nodes[i] = make_float2(thresholds[i], __int_as_float(features[i]));
    }
    __syncthreads();

    // --- Traversal: one element per thread ---
    const long b   = (long)blockIdx.x * BLOCK + tid;
    const float* row = obs + b * N_FEAT;

    int node = 0;
#pragma unroll
    for (int d = 0; d < DEPTH; ++d) {
        const float2 nd = nodes[node];          // ds_read_b64
        const int f = __float_as_int(nd.y);
        const float x = row[f];                 // per-lane global gather
        // go_left = (x <= t) -> 2n+1 ; else 2n+2.  Matches reference
        // exactly (including NaN ordering semantics).
        node = 2 * node + ((x <= nd.x) ? 1 : 2);
    }
    // node is now the absolute leaf id in [16383, 32766].

    // --- Epilogue: wave-cooperative coalesced output ---
    // Each wave owns 64 consecutive elements. Per iteration, 4 output rows
    // are written as float4 (16 lanes per row -> 1 KiB contiguous store).
    const int lane   = tid & 63;
    const long wbase = (long)blockIdx.x * BLOCK + (tid & ~63);
    const int r_lo   = lane >> 4;     // 0..3: which of the 4 rows this lane serves
    const int c4     = lane & 15;     // which float4 chunk of the 64-float row

#pragma unroll
    for (int it = 0; it < 16; ++it) {
        const int r = it * 4 + r_lo;
        const int leaf_r = __shfl(node, r, 64);   // broadcast leaf id of row r
        const float4 v = *(const float4*)(leaf_logits + (size_t)leaf_r * N_ACT + c4 * 4);
        *(float4*)(out + (wbase + r) * N_ACT + c4 * 4) = v;
    }
}

extern "C" void kernel_launch(void* const* d_in, const int* in_sizes, int n_in,
                              void* d_out, int out_size, void* d_ws, size_t ws_size,
                              hipStream_t stream) {
    const float* obs         = (const float*)d_in[0];
    const int*   features    = (const int*)  d_in[1];
    const float* thresholds  = (const float*)d_in[2];
    // d_in[3] = children_left, d_in[4] = children_right: unused — the tree is
    // complete by construction (children are 2i+1/2i+2, leaves at depth 14).
    const float* leaf_logits = (const float*)d_in[5];
    float*       out         = (float*)d_out;

    dim3 grid(BATCH / BLOCK);   // 256 blocks x 1024 threads = one thread/element
    tree_policy_kernel<<<grid, BLOCK, 0, stream>>>(obs, features, thresholds,
                                                   leaf_logits, out);
}